// Round 7
// baseline (134.822 us; speedup 1.0000x reference)
//
#include <hip/hip_runtime.h>
#include <hip/hip_bf16.h>

typedef short s8v   __attribute__((ext_vector_type(8)));
typedef float f32x4 __attribute__((ext_vector_type(4)));
typedef float f32x16 __attribute__((ext_vector_type(16)));

// RNE float -> bf16 bits
__device__ __forceinline__ unsigned short f2bf(float f) {
  unsigned int b = __float_as_uint(f);
  b += 0x7fffu + ((b >> 16) & 1u);
  return (unsigned short)(b >> 16);
}

// ---------------- prep_w ----------------
// wab  : [nt<4][kt<8][lane<64][j<8] = bf16 W[p=nt*16+(lane&15)][c=kt*32+8*(lane>>4)+j]  (16x16x32 frag, kernel_a)
// wfrag: [zt<4][kt2<64][lane<64][j<8] = bf16 Wproj[z=zt*32+(lane&31)][korig],
//        k'' = kt2*16 + 8*(lane>>5) + j;  d = k''>>5, c = k''&31, korig = c*32 + d   (32x32x16 B frag)
__global__ __launch_bounds__(256) void prep_w_kernel(
    const float* __restrict__ Wa, const float* __restrict__ Wb,
    const float* __restrict__ Wproj,
    unsigned short* __restrict__ wab, unsigned short* __restrict__ wfrag) {
  int gid = blockIdx.x * 256 + threadIdx.x;
  if (gid < 16384) {
    int e = gid;
    int j = e & 7, lane = (e >> 3) & 63, kt = (e >> 9) & 7, nt = e >> 12;
    int p = nt * 16 + (lane & 15);
    int c = kt * 32 + ((lane >> 4) << 3) + j;
    float v = (p < 32) ? Wa[p * 256 + c] : Wb[(p - 32) * 256 + c];
    wab[e] = f2bf(v);
  } else {
    int e = gid - 16384;                     // < 131072
    int j = e & 7, lane = (e >> 3) & 63, kt2 = (e >> 9) & 63, zt = e >> 15;
    int z = zt * 32 + (lane & 31);
    int kpp = kt2 * 16 + ((lane >> 5) << 3) + j;
    int d = kpp >> 5, c = kpp & 31;
    wfrag[e] = f2bf(Wproj[z * 1024 + c * 32 + d]);
  }
}

// ---------------- kernel_a: LN + MFMA projection + 32x32-fragment transpose ----------------
// block = (i, s-half): 768 blocks, 256 threads (4 waves).
// afrag: [i<384][kt<8][lane<64][j<8] = bf16 a_t[i*32 + (lane&31)][s = kt*16 + 8*(lane>>5) + j]
// bfrag: [j<384][kt<8][lane<64][j8]  = bf16 b_t[j*32 + (lane&31)][s]      (identical layout)
#define XS 264   // x_lds row stride (halfwords)
#define OS 66    // o_lds row stride (floats)
__global__ __launch_bounds__(256) void kernel_a(
    const float* __restrict__ msa, const float* __restrict__ gamma, const float* __restrict__ beta,
    const unsigned short* __restrict__ wab,
    unsigned short* __restrict__ afrag, unsigned short* __restrict__ bfrag) {
  __shared__ unsigned short xs[64 * XS];   // normalized x, bf16 [64 local s][256 c]
  __shared__ float os[64 * OS];            // proj result fp32 [64 local s][64 p]
  const int i  = blockIdx.x >> 1;
  const int sh = blockIdx.x & 1;           // s-half: s in [sh*64, sh*64+64)
  const int tid = threadIdx.x;
  const int w = tid >> 6, lane = tid & 63;
  const int gq = lane >> 4, nlo = lane & 15;

  const float4 g4  = *(const float4*)(gamma + lane * 4);
  const float4 be4 = *(const float4*)(beta  + lane * 4);

  // phase 1: LayerNorm, one row per wave per iter
  for (int it = 0; it < 16; ++it) {
    const int sl = it * 4 + w;
    const int s  = sh * 64 + sl;
    const float4 v = *(const float4*)(msa + (size_t)(s * 384 + i) * 256 + lane * 4);
    float sum = v.x + v.y + v.z + v.w;
    float sq  = fmaf(v.x, v.x, fmaf(v.y, v.y, fmaf(v.z, v.z, v.w * v.w)));
#pragma unroll
    for (int off = 32; off >= 1; off >>= 1) {
      sum += __shfl_xor(sum, off);
      sq  += __shfl_xor(sq,  off);
    }
    const float mu   = sum * (1.f / 256.f);
    const float var  = sq * (1.f / 256.f) - mu * mu;
    const float rstd = rsqrtf(var + 1e-5f);
    unsigned int lo = (unsigned int)f2bf((v.x - mu) * rstd * g4.x + be4.x)
                    | ((unsigned int)f2bf((v.y - mu) * rstd * g4.y + be4.y) << 16);
    unsigned int hi = (unsigned int)f2bf((v.z - mu) * rstd * g4.z + be4.z)
                    | ((unsigned int)f2bf((v.w - mu) * rstd * g4.w + be4.w) << 16);
    *(uint2*)&xs[sl * XS + lane * 4] = make_uint2(lo, hi);
  }
  __syncthreads();

  // phase 2: MFMA projection  o[s][p] = sum_c x[s][c] * W[p][c]; wave w owns rows w*16..+16
  const f32x4 z4 = {0.f, 0.f, 0.f, 0.f};
  f32x4 acc[4];
#pragma unroll
  for (int nt = 0; nt < 4; ++nt) acc[nt] = z4;
  for (int kt = 0; kt < 8; ++kt) {
    const s8v av = *(const s8v*)&xs[(w * 16 + nlo) * XS + kt * 32 + gq * 8];
#pragma unroll
    for (int nt = 0; nt < 4; ++nt) {
      const s8v bv = ((const s8v*)wab)[(nt * 8 + kt) * 64 + lane];
      acc[nt] = __builtin_amdgcn_mfma_f32_16x16x32_bf16(av, bv, acc[nt], 0, 0, 0);
    }
  }
#pragma unroll
  for (int nt = 0; nt < 4; ++nt)
#pragma unroll
    for (int r = 0; r < 4; ++r)
      os[(w * 16 + gq * 4 + r) * OS + nt * 16 + nlo] = acc[nt][r];
  __syncthreads();

  // phase 3: 32x32-fragment-order transposed write to afrag/bfrag
#pragma unroll
  for (int q = 0; q < 2; ++q) {
    const int set = q * 256 + tid;           // < 512
    const int lf  = set & 63;                // fragment lane
    const int ktl = (set >> 6) & 3;          // local k-tile (16 s each)
    const int mat = set >> 8;                // 0 = a, 1 = b
    const int gg  = lf >> 5;
    const int p   = mat * 32 + (lf & 31);
    s8v pk;
#pragma unroll
    for (int j = 0; j < 8; ++j)
      pk[j] = (short)f2bf(os[(ktl * 16 + 8 * gg + j) * OS + p]);
    unsigned short* dst = mat ? bfrag : afrag;
    *(s8v*)(dst + ((size_t)((i * 8 + sh * 4 + ktl) * 64 + lf)) * 8) = pk;
  }
}

// ---------------- kernel_main: fused outer-product + projection, 32x32 MFMA, 16 waves ----------------
// block = 8i x 8j (64 ij); 1024 threads (16 waves); 129 KB LDS -> 1 block/CU, 4 waves/SIMD.
// stage1: outer[m=(i,c)<256][n=(j,d)<256] = sum_s a b, K=128. wave grid 4m x 4n, wave tile 64x64,
//         acc = 4 x f32x16 (64 VGPR). t[row=iloc*8+jloc][k''] bf16 *1/128, k'' = d*32 + (c ^ 8*(d&3)), stride TSM.
// stage2: out[ij][z] = t x wfrag, M=64(2 m-tiles), N=128(4 z-tiles), K=1024(64 ksteps of 16).
//         waves = (zt<4, kh<4); wave covers both m-tiles, z-tile zt, k-quarter kh -> every LDS read
//         feeds 2 MFMAs, every wv read once. k-quarter partials reduced via LDS scratch (reuses t).
#define TSM 1032
__global__ __launch_bounds__(1024, 4) void kernel_main(
    const unsigned short* __restrict__ afrag, const unsigned short* __restrict__ bfrag,
    const unsigned short* __restrict__ wfrag, const float* __restrict__ bproj,
    float* __restrict__ out) {
  extern __shared__ unsigned short t[];      // [64][TSM] bf16; later reused as f32 scratch
  const int bid = blockIdx.x;                // no XCD swizzle (R1 evidence: lowest FETCH)
  const int bi = bid / 48, bj = bid % 48;
  const int tid = threadIdx.x;
  const int wave = tid >> 6, lane = tid & 63;
  const int g = lane >> 5, l31 = lane & 31;

  const s8v* ag = (const s8v*)afrag;
  const s8v* bg = (const s8v*)bfrag;
  const s8v* wg = (const s8v*)wfrag;

  // ---- stage 1 ----
  {
    const int wm = wave >> 2, wn = wave & 3;
    f32x16 a00 = {}, a01 = {}, a10 = {}, a11 = {};
#pragma unroll 2
    for (int kt = 0; kt < 8; ++kt) {
      const s8v av0 = ag[((bi * 8 + wm * 2 + 0) * 8 + kt) * 64 + lane];
      const s8v av1 = ag[((bi * 8 + wm * 2 + 1) * 8 + kt) * 64 + lane];
      const s8v bv0 = bg[((bj * 8 + wn * 2 + 0) * 8 + kt) * 64 + lane];
      const s8v bv1 = bg[((bj * 8 + wn * 2 + 1) * 8 + kt) * 64 + lane];
      a00 = __builtin_amdgcn_mfma_f32_32x32x16_bf16(av0, bv0, a00, 0, 0, 0);
      a01 = __builtin_amdgcn_mfma_f32_32x32x16_bf16(av0, bv1, a01, 0, 0, 0);
      a10 = __builtin_amdgcn_mfma_f32_32x32x16_bf16(av1, bv0, a10, 0, 0, 0);
      a11 = __builtin_amdgcn_mfma_f32_32x32x16_bf16(av1, bv1, a11, 0, 0, 0);
    }
    // store: D col = lane&31 = d; D row c = (r&3)+8*(r>>2)+4g; hw = d*32 + (c ^ 8*(d&3))
    const int xr = 8 * (l31 & 3);
#pragma unroll
    for (int mt = 0; mt < 2; ++mt)
#pragma unroll
      for (int nt = 0; nt < 2; ++nt) {
        const f32x16& a = (mt == 0) ? (nt == 0 ? a00 : a01) : (nt == 0 ? a10 : a11);
        const int row_t = (wm * 2 + mt) * 8 + wn * 2 + nt;
#pragma unroll
        for (int q = 0; q < 4; ++q) {
          const int c0 = q * 8 + 4 * g;
          const int hw = l31 * 32 + (c0 ^ xr);
          const unsigned int lo = (unsigned int)f2bf(a[q * 4 + 0] * 0.0078125f)
                                | ((unsigned int)f2bf(a[q * 4 + 1] * 0.0078125f) << 16);
          const unsigned int hi = (unsigned int)f2bf(a[q * 4 + 2] * 0.0078125f)
                                | ((unsigned int)f2bf(a[q * 4 + 3] * 0.0078125f) << 16);
          *(uint2*)&t[row_t * TSM + hw] = make_uint2(lo, hi);
        }
      }
  }
  __syncthreads();

  // ---- stage 2 ----
  const int zt = wave & 3, kh = wave >> 2;
  f32x16 p0 = {}, p1 = {};
#pragma unroll 4
  for (int k2 = 0; k2 < 16; ++k2) {
    const int kt2 = kh * 16 + k2;
    const int d = kt2 >> 1;
    const int hwb = d * 32 + ((((kt2 & 1) * 16) + 8 * g) ^ (8 * (d & 3)));
    const s8v wv = wg[((zt * 64 + kt2) * 64 + lane)];
    const s8v a0 = *(const s8v*)&t[l31 * TSM + hwb];
    const s8v a1 = *(const s8v*)&t[(32 + l31) * TSM + hwb];
    p0 = __builtin_amdgcn_mfma_f32_32x32x16_bf16(a0, wv, p0, 0, 0, 0);
    p1 = __builtin_amdgcn_mfma_f32_32x32x16_bf16(a1, wv, p1, 0, 0, 0);
  }
  __syncthreads();

  // ---- k-quarter reduction via LDS scratch (reuses t; 12 slots x 8 KB = 96 KB) ----
  float* sc = (float*)t;
  if (kh > 0) {
    const int slot = zt * 3 + (kh - 1);
#pragma unroll
    for (int r = 0; r < 16; ++r) {
      sc[((slot * 2 + 0) * 16 + r) * 64 + lane] = p0[r];
      sc[((slot * 2 + 1) * 16 + r) * 64 + lane] = p1[r];
    }
  }
  __syncthreads();
  if (kh == 0) {
#pragma unroll
    for (int s2 = 0; s2 < 3; ++s2) {
      const int slot = zt * 3 + s2;
#pragma unroll
      for (int r = 0; r < 16; ++r) {
        p0[r] += sc[((slot * 2 + 0) * 16 + r) * 64 + lane];
        p1[r] += sc[((slot * 2 + 1) * 16 + r) * 64 + lane];
      }
    }
    const int z = zt * 32 + l31;
    const float bz = bproj[z];
#pragma unroll
    for (int r = 0; r < 16; ++r) {
      {
        const int ij = (r & 3) + 8 * (r >> 2) + 4 * g;
        const int gi = bi * 8 + (ij >> 3), gj = bj * 8 + (ij & 7);
        out[(size_t)(gi * 384 + gj) * 128 + z] = p0[r] + bz;
      }
      {
        const int ij = 32 + (r & 3) + 8 * (r >> 2) + 4 * g;
        const int gi = bi * 8 + (ij >> 3), gj = bj * 8 + (ij & 7);
        out[(size_t)(gi * 384 + gj) * 128 + z] = p1[r] + bz;
      }
    }
  }
}

extern "C" void kernel_launch(void* const* d_in, const int* in_sizes, int n_in,
                              void* d_out, int out_size, void* d_ws, size_t ws_size,
                              hipStream_t stream) {
  const float* msa   = (const float*)d_in[0];
  const float* gam   = (const float*)d_in[1];
  const float* bet   = (const float*)d_in[2];
  const float* Wa    = (const float*)d_in[3];
  const float* Wb    = (const float*)d_in[4];
  const float* Wproj = (const float*)d_in[5];
  const float* bpr   = (const float*)d_in[6];
  float* out = (float*)d_out;

  // workspace layout (bf16 elems): afrag 3MB, bfrag 3MB, wab 32KB, wfrag 256KB
  if (ws_size < 6586368) return;
  unsigned short* afrag = (unsigned short*)d_ws;
  unsigned short* bfrag = afrag + 1572864;
  unsigned short* wab   = bfrag + 1572864;
  unsigned short* wfr   = wab + 16384;

  (void)hipFuncSetAttribute(reinterpret_cast<const void*>(kernel_main),
                            hipFuncAttributeMaxDynamicSharedMemorySize, 64 * TSM * 2);

  prep_w_kernel<<<576, 256, 0, stream>>>(Wa, Wb, Wproj, wab, wfr);
  kernel_a<<<768, 256, 0, stream>>>(msa, gam, bet, wab, afrag, bfrag);
  kernel_main<<<2304, 1024, 64 * TSM * 2, stream>>>(afrag, bfrag, wfr, bpr, out);
}

// Round 8
// 130.023 us; speedup vs baseline: 1.0369x; 1.0369x over previous
//
#include <hip/hip_runtime.h>
#include <hip/hip_bf16.h>

typedef short s8v   __attribute__((ext_vector_type(8)));
typedef float f32x4 __attribute__((ext_vector_type(4)));
typedef float f32x16 __attribute__((ext_vector_type(16)));

// RNE float -> bf16 bits
__device__ __forceinline__ unsigned short f2bf(float f) {
  unsigned int b = __float_as_uint(f);
  b += 0x7fffu + ((b >> 16) & 1u);
  return (unsigned short)(b >> 16);
}
// packed pair: lo halfword = bf16(x), hi halfword = bf16(y)
__device__ __forceinline__ unsigned int cvtpk(float x, float y) {
  unsigned int r;
  asm("v_cvt_pk_bf16_f32 %0, %1, %2" : "=v"(r) : "v"(x), "v"(y));
  return r;
}

// ---------------- prep_w ----------------
// wab  : [nt<4][kt<8][lane<64][j<8] = bf16 W[p=nt*16+(lane&15)][c=kt*32+8*(lane>>4)+j]  (16x16x32, kernel_a)
// wfrag: [zt<4][kt2<64][lane<64][j<8] = bf16 Wproj[z=zt*32+(lane&31)][korig],
//        k'' = kt2*16 + 8*(lane>>5) + j;  d = k''>>5, c = k''&31, korig = c*32 + d
__global__ __launch_bounds__(256) void prep_w_kernel(
    const float* __restrict__ Wa, const float* __restrict__ Wb,
    const float* __restrict__ Wproj,
    unsigned short* __restrict__ wab, unsigned short* __restrict__ wfrag) {
  int gid = blockIdx.x * 256 + threadIdx.x;
  if (gid < 16384) {
    int e = gid;
    int j = e & 7, lane = (e >> 3) & 63, kt = (e >> 9) & 7, nt = e >> 12;
    int p = nt * 16 + (lane & 15);
    int c = kt * 32 + ((lane >> 4) << 3) + j;
    float v = (p < 32) ? Wa[p * 256 + c] : Wb[(p - 32) * 256 + c];
    wab[e] = f2bf(v);
  } else {
    int e = gid - 16384;                     // < 131072
    int j = e & 7, lane = (e >> 3) & 63, kt2 = (e >> 9) & 63, zt = e >> 15;
    int z = zt * 32 + (lane & 31);
    int kpp = kt2 * 16 + ((lane >> 5) << 3) + j;
    int d = kpp >> 5, c = kpp & 31;
    wfrag[e] = f2bf(Wproj[z * 1024 + c * 32 + d]);
  }
}

// ---------------- kernel_a: LN + MFMA projection + fragment transpose ----------------
// block = (i, s-half): 768 blocks, 256 threads (4 waves).
// afrag: [i<384][kt<8][lane<64][j<8] = bf16 (a_t[i*32+(lane&31)][s=kt*16+8*(lane>>5)+j]) * (1/128)
// bfrag: [bj<48][nt<8][kt<8][lane<64][j<8] = bf16 b_t[(bj*8+jl)*32+dl][s],
//        where nt*32 + (lane&31) = dl*8 + jl   (n reordered d-major for chunk-aligned 32x32 n-tiles)
#define XS 264   // x_lds row stride (halfwords)
#define OS 66    // o_lds row stride (floats)
__global__ __launch_bounds__(256) void kernel_a(
    const float* __restrict__ msa, const float* __restrict__ gamma, const float* __restrict__ beta,
    const unsigned short* __restrict__ wab,
    unsigned short* __restrict__ afrag, unsigned short* __restrict__ bfrag) {
  __shared__ unsigned short xs[64 * XS];   // normalized x, bf16 [64 local s][256 c]
  __shared__ float os[64 * OS];            // proj result fp32 [64 local s][64 p]
  const int i  = blockIdx.x >> 1;
  const int sh = blockIdx.x & 1;           // s-half: s in [sh*64, sh*64+64)
  const int tid = threadIdx.x;
  const int w = tid >> 6, lane = tid & 63;
  const int gq = lane >> 4, nlo = lane & 15;

  const float4 g4  = *(const float4*)(gamma + lane * 4);
  const float4 be4 = *(const float4*)(beta  + lane * 4);

  // phase 1: LayerNorm, one row per wave per iter
  for (int it = 0; it < 16; ++it) {
    const int sl = it * 4 + w;
    const int s  = sh * 64 + sl;
    const float4 v = *(const float4*)(msa + (size_t)(s * 384 + i) * 256 + lane * 4);
    float sum = v.x + v.y + v.z + v.w;
    float sq  = fmaf(v.x, v.x, fmaf(v.y, v.y, fmaf(v.z, v.z, v.w * v.w)));
#pragma unroll
    for (int off = 32; off >= 1; off >>= 1) {
      sum += __shfl_xor(sum, off);
      sq  += __shfl_xor(sq,  off);
    }
    const float mu   = sum * (1.f / 256.f);
    const float var  = sq * (1.f / 256.f) - mu * mu;
    const float rstd = rsqrtf(var + 1e-5f);
    unsigned int lo = (unsigned int)f2bf((v.x - mu) * rstd * g4.x + be4.x)
                    | ((unsigned int)f2bf((v.y - mu) * rstd * g4.y + be4.y) << 16);
    unsigned int hi = (unsigned int)f2bf((v.z - mu) * rstd * g4.z + be4.z)
                    | ((unsigned int)f2bf((v.w - mu) * rstd * g4.w + be4.w) << 16);
    *(uint2*)&xs[sl * XS + lane * 4] = make_uint2(lo, hi);
  }
  __syncthreads();

  // phase 2: MFMA projection  o[s][p] = sum_c x[s][c] * W[p][c]; wave w owns rows w*16..+16
  const f32x4 z4 = {0.f, 0.f, 0.f, 0.f};
  f32x4 acc[4];
#pragma unroll
  for (int nt = 0; nt < 4; ++nt) acc[nt] = z4;
  for (int kt = 0; kt < 8; ++kt) {
    const s8v av = *(const s8v*)&xs[(w * 16 + nlo) * XS + kt * 32 + gq * 8];
#pragma unroll
    for (int nt = 0; nt < 4; ++nt) {
      const s8v bv = ((const s8v*)wab)[(nt * 8 + kt) * 64 + lane];
      acc[nt] = __builtin_amdgcn_mfma_f32_16x16x32_bf16(av, bv, acc[nt], 0, 0, 0);
    }
  }
#pragma unroll
  for (int nt = 0; nt < 4; ++nt)
#pragma unroll
    for (int r = 0; r < 4; ++r)
      os[(w * 16 + gq * 4 + r) * OS + nt * 16 + nlo] = acc[nt][r];
  __syncthreads();

  // phase 3a: afrag write (a scaled by 1/128 here; exact pow2, no extra bf16 error)
  {
    const int lf = tid & 63, ktl = tid >> 6;       // ktl < 4 (16-s granule)
    const int gg = lf >> 5;
    const int c  = lf & 31;
    s8v pk;
#pragma unroll
    for (int j8 = 0; j8 < 8; ++j8)
      pk[j8] = (short)f2bf(os[(ktl * 16 + 8 * gg + j8) * OS + c] * 0.0078125f);
    *(s8v*)(afrag + ((size_t)((i * 8 + sh * 4 + ktl) * 64 + lf)) * 8) = pk;
  }
  // phase 3b: bfrag write, d-major n order: slot (nt, l31) <- dl = (nt*32+l31)>>3 when (nt*32+l31)&7 == j&7
  {
    const int dl = tid & 31, ktl = (tid >> 5) & 3, gg = tid >> 7;  // 32*4*2 = 256
    const int jl = i & 7, bj = i >> 3;
    const int nt = dl >> 2;
    const int l31 = (dl & 3) * 8 + jl;
    const int lf = gg * 32 + l31;
    s8v pk;
#pragma unroll
    for (int j8 = 0; j8 < 8; ++j8)
      pk[j8] = (short)f2bf(os[(ktl * 16 + 8 * gg + j8) * OS + 32 + dl]);
    *(s8v*)(bfrag + ((size_t)(((bj * 8 + nt) * 8 + sh * 4 + ktl) * 64 + lf)) * 8) = pk;
  }
}

// ---------------- kernel_main: fused, d-half chunked (register-resident), 2 blocks/CU ----------------
// block = 8i x 8j (64 ij); 512 thr (8 waves); 66 KB LDS, <=128 regs -> 2 blocks/CU.
// per chunk dc (d-half, k''-chunk of 512):
//   stage1: M=256 (i,c), N=128 (n = dlc*8+jl): wave grid 4m x 2n, wave tile 64x64, acc[2][2] f32x16.
//   t[row = iloc*8+jl <64][hw = (dlc*32 + c) ^ 8*(row&7)] bf16, stride TSC.
//   stage2: 8 waves = 4z x 2m: wave = 32z x 32ij, K=512/chunk (32 ksteps), p f32x16 persists. No scratch.
#define TSC 528
__global__ __launch_bounds__(512, 4) void kernel_main(
    const unsigned short* __restrict__ afrag, const unsigned short* __restrict__ bfrag,
    const unsigned short* __restrict__ wfrag, const float* __restrict__ bproj,
    float* __restrict__ out) {
  extern __shared__ unsigned short t[];      // [64][TSC]
  const int bid = blockIdx.x;
  const int bi = bid / 48, bj = bid % 48;
  const int tid = threadIdx.x;
  const int wave = tid >> 6, lane = tid & 63;
  const int g = lane >> 5, l31 = lane & 31;
  const int jl7 = l31 & 7;

  const s8v* ag = (const s8v*)afrag;
  const s8v* bg = (const s8v*)bfrag;
  const s8v* wg = (const s8v*)wfrag;

  const int wm = wave >> 1, wn = wave & 1;   // stage-1 grid 4m x 2n
  const int zt = wave & 3, mts = wave >> 2;  // stage-2 grid 4z x 2m

  f32x16 p = {};                             // stage-2 accumulator, persists across chunks

#pragma unroll 1
  for (int dc = 0; dc < 2; ++dc) {
    // ---- stage 1: chunk dc, acc fully register-resident ----
    f32x16 a00 = {}, a01 = {}, a10 = {}, a11 = {};
#pragma unroll 2
    for (int kt = 0; kt < 8; ++kt) {
      const s8v av0 = ag[((bi * 8 + wm * 2 + 0) * 8 + kt) * 64 + lane];
      const s8v av1 = ag[((bi * 8 + wm * 2 + 1) * 8 + kt) * 64 + lane];
      const s8v bv0 = bg[(((bj * 8 + dc * 4 + wn * 2 + 0) * 8) + kt) * 64 + lane];
      const s8v bv1 = bg[(((bj * 8 + dc * 4 + wn * 2 + 1) * 8) + kt) * 64 + lane];
      a00 = __builtin_amdgcn_mfma_f32_32x32x16_bf16(av0, bv0, a00, 0, 0, 0);
      a01 = __builtin_amdgcn_mfma_f32_32x32x16_bf16(av0, bv1, a01, 0, 0, 0);
      a10 = __builtin_amdgcn_mfma_f32_32x32x16_bf16(av1, bv0, a10, 0, 0, 0);
      a11 = __builtin_amdgcn_mfma_f32_32x32x16_bf16(av1, bv1, a11, 0, 0, 0);
    }

    if (dc) __syncthreads();                 // previous chunk's stage-2 reads complete

    // ---- t-write: row = iloc*8 + jl (jl = l31&7); dlc = (wn*2+ntb)*4 + (l31>>3);
    //      hw = (dlc*32 + q*8 + 4g [+r&3 in-vector]) ^ (8*jl) ----
#pragma unroll
    for (int mta = 0; mta < 2; ++mta)
#pragma unroll
      for (int ntb = 0; ntb < 2; ++ntb) {
        const f32x16& a = (mta == 0) ? (ntb == 0 ? a00 : a01) : (ntb == 0 ? a10 : a11);
        const int row = ((wm * 2 + mta) * 8) + jl7;
        const int dlc = (wn * 2 + ntb) * 4 + (l31 >> 3);
#pragma unroll
        for (int q = 0; q < 4; ++q) {
          const int hw = (dlc * 32 + q * 8 + 4 * g) ^ (8 * jl7);
          const unsigned int lo = cvtpk(a[q * 4 + 0], a[q * 4 + 1]);
          const unsigned int hi = cvtpk(a[q * 4 + 2], a[q * 4 + 3]);
          *(uint2*)&t[row * TSC + hw] = make_uint2(lo, hi);
        }
      }
    __syncthreads();

    // ---- stage 2: wave (zt, mts) = 32z x 32ij, 32 ksteps of K=16 ----
#pragma unroll 4
    for (int ks = 0; ks < 32; ++ks) {
      const int hwb = (ks * 16 + 8 * g) ^ (8 * jl7);
      const s8v a2 = *(const s8v*)&t[(mts * 32 + l31) * TSC + hwb];
      const s8v wv = wg[((zt * 64 + dc * 32 + ks) * 64 + lane)];
      p = __builtin_amdgcn_mfma_f32_32x32x16_bf16(a2, wv, p, 0, 0, 0);
    }
  }

  // ---- epilogue ----
  const int z = zt * 32 + l31;
  const float bz = bproj[z];
#pragma unroll
  for (int r = 0; r < 16; ++r) {
    const int ij = mts * 32 + (r & 3) + 8 * (r >> 2) + 4 * g;
    const int gi = bi * 8 + (ij >> 3), gj = bj * 8 + (ij & 7);
    out[(size_t)(gi * 384 + gj) * 128 + z] = p[r] + bz;
  }
}

extern "C" void kernel_launch(void* const* d_in, const int* in_sizes, int n_in,
                              void* d_out, int out_size, void* d_ws, size_t ws_size,
                              hipStream_t stream) {
  const float* msa   = (const float*)d_in[0];
  const float* gam   = (const float*)d_in[1];
  const float* bet   = (const float*)d_in[2];
  const float* Wa    = (const float*)d_in[3];
  const float* Wb    = (const float*)d_in[4];
  const float* Wproj = (const float*)d_in[5];
  const float* bpr   = (const float*)d_in[6];
  float* out = (float*)d_out;

  // workspace layout (bf16 elems): afrag 3MB, bfrag 3MB, wab 32KB, wfrag 256KB
  if (ws_size < 6586368) return;
  unsigned short* afrag = (unsigned short*)d_ws;
  unsigned short* bfrag = afrag + 1572864;
  unsigned short* wab   = bfrag + 1572864;
  unsigned short* wfr   = wab + 16384;

  (void)hipFuncSetAttribute(reinterpret_cast<const void*>(kernel_main),
                            hipFuncAttributeMaxDynamicSharedMemorySize, 64 * TSC * 2);

  prep_w_kernel<<<576, 256, 0, stream>>>(Wa, Wb, Wproj, wab, wfr);
  kernel_a<<<768, 256, 0, stream>>>(msa, gam, bet, wab, afrag, bfrag);
  kernel_main<<<2304, 512, 64 * TSC * 2, stream>>>(afrag, bfrag, wfr, bpr, out);
}